// Round 7
// baseline (113.083 us; speedup 1.0000x reference)
//
#include <hip/hip_runtime.h>
#include <stdint.h>

typedef unsigned short u16;
typedef unsigned int u32;
typedef unsigned long long u64;
typedef unsigned char u8;

typedef __attribute__((ext_vector_type(4))) int   i32x4;
typedef __attribute__((ext_vector_type(8))) int   i32x8;
typedef __attribute__((ext_vector_type(4))) float f32x4;

// ---------------- workspace layout (bytes) ----------------
#define OFF_WQ4  0u                                  // fp4 e2m1 W, fragment order:
// 16B slot = ks*2048 + (j*4 + kblock), ks = k>>7, kblock = (k>>5)&3,
// elem i = k&31 -> byte i>>1, even i = lo nibble (matches A spread order)
#define WQ4_BYTES (2u * 32768u)                      // 64 KiB
#define OFF_SCL  (OFF_WQ4 + WQ4_BYTES)               // float[256]: colmax/12

// ---- 8 bits -> 8 e2m1 nibbles (0x0 / 0x2) via v_perm 2-bit->byte LUT ----
__device__ __forceinline__ u32 nib_perm(u32 byte) {
    u32 t1 = byte | (byte << 6);
    u32 t2 = t1 | (t1 << 12);
    u32 sel = t2 & 0x03030303u;
    // LUT bytes: idx0->0x00 idx1->0x02 idx2->0x20 idx3->0x22
    return __builtin_amdgcn_perm(0x22200200u, 0x22200200u, sel);
}

// ---------------- kernel 1: W prep (256 blocks) ----------------
__global__ __launch_bounds__(256) void prep_kernel(
    const float* __restrict__ lin_w, uint8_t* __restrict__ ws) {
    __shared__ float red[256];
    __shared__ u8 nib[256];
    int j = blockIdx.x, k = threadIdx.x;
    float wv = lin_w[j * 256 + k];
    red[k] = fabsf(wv);
    __syncthreads();
    #pragma unroll
    for (int s = 128; s > 0; s >>= 1) {
        if (k < s) red[k] = fmaxf(red[k], red[k + s]);
        __syncthreads();
    }
    float m = red[0];
    float S = (m > 0.f) ? 6.0f / m : 0.f;
    float v6 = wv * S;
    float av = fabsf(v6);
    int code;
    if      (av < 0.25f) code = 0;
    else if (av < 0.75f) code = 1;
    else if (av < 1.25f) code = 2;
    else if (av < 1.75f) code = 3;
    else if (av < 2.5f)  code = 4;
    else if (av < 3.5f)  code = 5;
    else if (av < 5.0f)  code = 6;
    else                 code = 7;
    nib[k] = (u8)(((v6 < 0.f && code) ? 8 : 0) | code);
    __syncthreads();
    if (k < 128) {
        u8 byte = (u8)(nib[2 * k] | (nib[2 * k + 1] << 4));
        int ks = k >> 6, kb = (k >> 4) & 3, bi = k & 15;
        (ws + OFF_WQ4)[ks * 32768 + (j * 4 + kb) * 16 + bi] = byte;
    }
    if (k == 0) ((float*)(ws + OFF_SCL))[j] = m * (1.0f / 12.0f);
}

// ---------------- kernel 2: FUSED encoder + t-split GEMM + scan --------
// 512 blocks x 512 threads (8 waves), 2 blocks/CU, 16 waves/CU.
// Wave (th = w>>2, jq = w&3): t-half x j-quarter -> acc[4][4] = 64 f32/lane
// (HALF of R6's 128: breaks the register occupancy wall; launch_bounds
// (512,4) caps unified regs at 128 -> 4 waves/SIMD).
// Encoder: ALL 512 threads, scalar chain each (1 chain/thread; all SIMDs
// active). bits u32[4 seq][8 hc][128 l] = 16 KB LDS.
// Epilogue: cross-wave phased ZW: 2 x 32 KB ping-pong buffers, XOR-swizzled
// stride-32 rows (slot ^= row&7; write lanes & read lanes both hit the
// 128 B/clk floor). th0 owns t0..63 (ph0,1), th1 owns t64..127 (ph2,3).
// Scanning threads (tid<256) ARE the th0 waves: their acc is dead after
// their phase writes -> registers free for the scan.
#define PHW(BUF, MB)                                                     \
    _Pragma("unroll") for (int mm = 0; mm < 2; ++mm) {                   \
        int co = ((mm << 4) | (quad << 2)) ^ lx4;                        \
        _Pragma("unroll") for (int nf = 0; nf < 4; ++nf)                 \
            *(f32x4*)((BUF) + (jq * 64 + nf * 16 + l15) * 32 + co) =     \
                acc[(MB) + mm][nf];                                      \
    }

#define SCAN(BUF, LAST)                                                  \
    _Pragma("unroll") for (int g = 0; g < 8; ++g) {                      \
        f32x4 z4 = *(const f32x4*)((BUF) + tid * 32 + ((g << 2) ^ lx4)); \
        _Pragma("unroll") for (int r = 0; r < 4; ++r) {                  \
            u = fmaf(0.5f, u, z4[r]);                                    \
            bool sp = (u >= uth);                                        \
            if ((LAST) && g == 7 && r == 3) sOut = sp ? 1.f : 0.f;       \
            u = sp ? urst : u;                                           \
        }                                                                \
    }

__global__ __launch_bounds__(512, 4) void enc_gemm_kernel(
    const float* __restrict__ x,
    const float* __restrict__ conv_w, const float* __restrict__ conv_b,
    const float* __restrict__ gamma,  const float* __restrict__ beta,
    const float* __restrict__ mean,   const float* __restrict__ var,
    const uint4* __restrict__ wq4,
    const float* __restrict__ lin_b,  const float* __restrict__ sclp,
    float* __restrict__ out) {
    __shared__ __align__(16) uint8_t smem[81920];
    u32*   bits = (u32*)smem;                        // [4][8][128]
    f32x4* cfl  = (f32x4*)(smem + 16384);            // overlay on bufA
    float* bufA = (float*)(smem + 16384);            // [256 j][32] swizzled
    float* bufB = (float*)(smem + 49152);

    int tid  = threadIdx.x;
    int blk  = blockIdx.x;                           // 0..511
    int lane = tid & 63;
    int w    = tid >> 6;                             // 0..7
    int th   = w >> 2;                               // t-half
    int jq   = w & 3;                                // j-quarter
    int l15  = lane & 15;
    int quad = lane >> 4;
    int lx4  = (lane & 7) << 2;                      // swizzle key (floats)
    int b0   = blk >> 4;                             // 0..31
    int cpair = (blk & 15) * 2;

    // ---- scan constants (j = tid, scanning threads only) ----
    float uth = 0.f, urst = 0.f;
    if (tid < 256) {
        float bias = lin_b[tid];
        float zscg = fmaxf(sclp[tid], 1e-37f);       // colmax/12, guarded
        uth  = (1.0f - bias) / zscg;                 // spike: u >= uth
        urst = (0.0f - bias) / zscg;                 // reset (v=0)
    }

    // ---- BN fold (coeffs pre-halved: folds tau=2) ----
    if (tid < 256) {
        int h = tid;
        float inv = gamma[h] / sqrtf(var[h] + 1e-5f);
        float K = (conv_b[h] - mean[h]) * inv + beta[h];
        f32x4 cc = {conv_w[h * 3 + 0] * inv * 0.5f,
                    conv_w[h * 3 + 1] * inv * 0.5f,
                    conv_w[h * 3 + 2] * inv * 0.5f, K * 0.5f};
        cfl[h] = cc;
    }

    // ---- encoder: scalar chain, thread = (bh, ch, l) ----
    int l  = tid & 127;
    int ch = (tid >> 7) & 1;
    int bh = tid >> 8;
    int xb = b0 * 4096 + l * 32 + cpair + ch + bh * 131072;
    float xbv = x[xb];
    float xav = (l > 0)   ? x[xb - 32] : 0.f;
    float xcv = (l < 127) ? x[xb + 32] : 0.f;
    u32* dst = bits + (bh * 2 + ch) * 1024 + l;      // seq = bh*2+ch

    __syncthreads();                                 // cfl visible
    {
        float v = 0.f;
        #pragma unroll 1
        for (int hc = 0; hc < 8; ++hc) {
            u32 cc = 0;
            #pragma unroll
            for (int k = 0; k < 32; ++k) {
                f32x4 a4 = cfl[hc * 32 + k];
                float e = fmaf(a4[2], xcv, a4[3]);
                e = fmaf(a4[1], xbv, e);
                e = fmaf(a4[0], xav, e);
                v = fmaf(0.5f, v, e);                // v = v/2 + e (pre-halved)
                bool sp = (v >= 1.0f);
                cc = (cc << 1) | (u32)sp;
                v = sp ? 0.f : v;
            }
            dst[hc * 128] = __builtin_bitreverse32(cc); // bit i = spike(hc*32+i)
        }
    }
    __syncthreads();                                 // bits ready, cfl dead

    // ---- GEMM + phased epilogue, 4 sequences ----
    int lb = jq * 256 + l15 * 4 + quad;              // per-lane W slot base
    const u32* bp = bits + quad * 128 + th * 64 + l15;

    #pragma unroll 1
    for (int s = 0; s < 4; ++s) {
        // A words: row l = th*64 + mf*16 + l15, chunk hc = ks*4+quad
        u32 aw[4][2];
        #pragma unroll
        for (int mf = 0; mf < 4; ++mf)
            #pragma unroll
            for (int ks = 0; ks < 2; ++ks)
                aw[mf][ks] = bp[s * 1024 + ks * 512 + mf * 16];

        f32x4 acc[4][4];
        #pragma unroll
        for (int mf = 0; mf < 4; ++mf)
            #pragma unroll
            for (int nf = 0; nf < 4; ++nf) {
                f32x4 z = {0.f, 0.f, 0.f, 0.f};
                acc[mf][nf] = z;
            }

        i32x8 afr;
        afr[4] = 0; afr[5] = 0; afr[6] = 0; afr[7] = 0;

        #pragma unroll
        for (int ks = 0; ks < 2; ++ks) {
            // B fragments per ks (16 regs live; L2-hot reload keeps VGPR<=128)
            i32x8 bfr[4];
            #pragma unroll
            for (int nf = 0; nf < 4; ++nf) {
                i32x4 bv = ((const i32x4*)wq4)[(size_t)(ks * 2048 + nf * 64 + lb)];
                bfr[nf][0] = bv[0]; bfr[nf][1] = bv[1];
                bfr[nf][2] = bv[2]; bfr[nf][3] = bv[3];
                bfr[nf][4] = 0; bfr[nf][5] = 0; bfr[nf][6] = 0; bfr[nf][7] = 0;
            }
            #pragma unroll
            for (int mf = 0; mf < 4; ++mf) {
                u32 wb = aw[mf][ks];
                afr[0] = (int)nib_perm(wb & 0xFFu);
                afr[1] = (int)nib_perm((wb >> 8) & 0xFFu);
                afr[2] = (int)nib_perm((wb >> 16) & 0xFFu);
                afr[3] = (int)nib_perm(wb >> 24);
                #pragma unroll
                for (int nf = 0; nf < 4; ++nf) {
                    acc[mf][nf] =
                        __builtin_amdgcn_mfma_scale_f32_16x16x128_f8f6f4(
                            afr, bfr[nf], acc[mf][nf], 4, 4,  // fp4 x fp4
                            0, 0x7F7F7F7F, 0, 0x7F7F7F7F);    // scales 1.0
                }
            }
        }

        // ---- phased cross-wave epilogue + u-scan ----
        float u = urst, sOut = 0.f;
        if (th == 0) { PHW(bufA, 0) PHW(bufB, 2) }   // ph0 (t0..31), ph1
        __syncthreads();                             // bar1: ph0,ph1 ready
        if (tid < 256) { SCAN(bufA, 0) }             // scan ph0
        __syncthreads();                             // bar2: bufA free
        if (th == 1) { PHW(bufA, 0) }                // ph2 (t64..95)
        if (tid < 256) { SCAN(bufB, 0) }             // scan ph1
        __syncthreads();                             // bar3: bufB free, ph2 ready
        if (th == 1) { PHW(bufB, 2) }                // ph3 (t96..127)
        if (tid < 256) { SCAN(bufA, 0) }             // scan ph2
        __syncthreads();                             // bar4: ph3 ready
        if (tid < 256) {
            SCAN(bufB, 1)                            // scan ph3 -> sOut
            int n = b0 * 32 + cpair + (s & 1) + (s >> 1) * 1024;
            out[(size_t)n * 256 + tid]           = sOut;   // (64,1,8192)
            out[524288u + (size_t)n * 256 + tid] = sOut;   // (64,8192)
        }
        __syncthreads();                             // bar5: bufs free for s+1
    }
}

// ---------------- launcher ----------------
extern "C" void kernel_launch(void* const* d_in, const int* in_sizes, int n_in,
                              void* d_out, int out_size, void* d_ws, size_t ws_size,
                              hipStream_t stream) {
    const float* x      = (const float*)d_in[0];
    const float* conv_w = (const float*)d_in[1];
    const float* conv_b = (const float*)d_in[2];
    const float* gamma  = (const float*)d_in[3];
    const float* beta   = (const float*)d_in[4];
    const float* mean   = (const float*)d_in[5];
    const float* var    = (const float*)d_in[6];
    const float* lin_w  = (const float*)d_in[7];
    const float* lin_b  = (const float*)d_in[8];
    uint8_t* ws = (uint8_t*)d_ws;
    float* out = (float*)d_out;

    hipLaunchKernelGGL(prep_kernel, dim3(256), dim3(256), 0, stream,
                       lin_w, ws);
    hipLaunchKernelGGL(enc_gemm_kernel, dim3(512), dim3(512), 0, stream,
                       x, conv_w, conv_b, gamma, beta, mean, var,
                       (const uint4*)(ws + OFF_WQ4), lin_b,
                       (const float*)(ws + OFF_SCL), out);
}